// Round 1
// baseline (24053.351 us; speedup 1.0000x reference)
//
#include <hip/hip_runtime.h>
#include <hip/hip_fp16.h>

#define DEVINL __device__ __forceinline__

constexpr int Cc = 53;      // channels
constexpr int Tt = 256;     // timesteps
constexpr int C2 = 2809;    // 53*53

DEVINL float sigmoidf_(float v) { return 1.f / (1.f + __expf(-v)); }

DEVINL float4 load4h(const __half* p) {
    union { float2 f; __half2 h[2]; } u;
    u.f = *(const float2*)p;
    float2 lo = __half22float2(u.h[0]);
    float2 hi = __half22float2(u.h[1]);
    return make_float4(lo.x, lo.y, hi.x, hi.y);
}

// One MLP layer: out[56][128] = act(in[56][K] @ W[128][K]^T + bias)
// in: LDS (float stride 68 for K=64, or __half stride 132 for K=128)
// out: LDS __half stride 132. Supports in-place (reads all, barrier, writes).
template<int K, bool INHALF, bool RELU>
DEVINL void mlp_layer(const void* __restrict__ inp,
                      const float* __restrict__ W,
                      const float* __restrict__ bias,
                      __half* __restrict__ outp,
                      int colg, int rsub)
{
    constexpr int INSTRIDE = INHALF ? 132 : 68;
    float a0[7], a1[7];
#pragma unroll
    for (int r = 0; r < 7; r++) { a0[r] = 0.f; a1[r] = 0.f; }
    const float4* w0p = (const float4*)(W + colg * K);
    const float4* w1p = (const float4*)(W + (colg + 64) * K);
#pragma unroll 4
    for (int kc = 0; kc < K / 4; kc++) {
        float4 w0 = w0p[kc];
        float4 w1 = w1p[kc];
#pragma unroll
        for (int r = 0; r < 7; r++) {
            int c = rsub + 8 * r;   // 0..55, pad rows computed harmlessly
            float4 iv;
            if constexpr (INHALF)
                iv = load4h((const __half*)inp + c * INSTRIDE + kc * 4);
            else
                iv = *(const float4*)((const float*)inp + c * INSTRIDE + kc * 4);
            a0[r] += iv.x * w0.x + iv.y * w0.y + iv.z * w0.z + iv.w * w0.w;
            a1[r] += iv.x * w1.x + iv.y * w1.y + iv.z * w1.z + iv.w * w1.w;
        }
    }
    __syncthreads();   // all reads done -> safe to write in place
    float b0 = bias[colg], b1 = bias[colg + 64];
#pragma unroll
    for (int r = 0; r < 7; r++) {
        int c = rsub + 8 * r;
        float v0 = a0[r] + b0;
        float v1 = a1[r] + b1;
        if constexpr (RELU) { v0 = fmaxf(v0, 0.f); v1 = fmaxf(v1, 0.f); }
        outp[c * 132 + colg]      = __float2half(v0);
        outp[c * 132 + colg + 64] = __float2half(v1);
    }
    __syncthreads();
}

__global__ __launch_bounds__(512)
void scan_kernel(const float* __restrict__ x,
                 const float* __restrict__ w_emb,
                 const float* __restrict__ b_emb,
                 const float* __restrict__ w_ih,
                 const float* __restrict__ w_hh,
                 const float* __restrict__ b_ih,
                 const float* __restrict__ b_hh,
                 const float* __restrict__ qw0, const float* __restrict__ qb0,
                 const float* __restrict__ qw1, const float* __restrict__ qb1,
                 const float* __restrict__ qw2, const float* __restrict__ qb2,
                 const float* __restrict__ kw0, const float* __restrict__ kb0,
                 const float* __restrict__ kw1, const float* __restrict__ kb1,
                 const float* __restrict__ kw2, const float* __restrict__ kb2,
                 const float* __restrict__ gate_bias,
                 const float* __restrict__ pred_w,
                 const float* __restrict__ pred_b,
                 float* __restrict__ out_meanF,
                 float* __restrict__ out_mix,
                 float* __restrict__ out_pred,
                 float* __restrict__ out_xcopy)
{
    // padded rows (56) so compute loops need no row guards; pad stays inert.
    __shared__ __align__(16) float  hh[56][68];    // h / h_gru / h_new (fp32 state)
    __shared__ __align__(16) __half qs[56][132];   // q chain
    __shared__ __align__(16) __half ks[56][132];   // k chain
    __shared__ __align__(16) float  tr[56][56];    // transfer
    __shared__ float xc[56];
    __shared__ float ab[2][192];                   // alpha, beta
    __shared__ float red[8];
    __shared__ float s_inv;

    const int b    = blockIdx.x;
    const int tid  = threadIdx.x;
    const int lane = tid & 63;
    const int wv   = tid >> 6;
    const int colg = (wv << 3) + (lane >> 3);      // 0..63 column index
    const int rsub = lane & 7;                     // rows c = rsub + 8*r

    // alpha/beta: gi = x*alpha + beta  (embedding GEMM folded away)
    if (tid < 192) {
        float av = 0.f, bv = 0.f;
        for (int e = 0; e < 64; e++) {
            float w = w_ih[tid * 64 + e];
            av += w * w_emb[e];
            bv += w * b_emb[e];
        }
        ab[0][tid] = av;
        ab[1][tid] = bv + b_ih[tid];
    }
    for (int i = tid; i < 56 * 68; i += 512) (&hh[0][0])[i] = 0.f;
    for (int i = tid; i < 56 * 56; i += 512) (&tr[0][0])[i] = 0.f;
    if (tid < 56) xc[tid] = 0.f;
    __syncthreads();

    const float a_r = ab[0][colg], a_z = ab[0][64 + colg], a_n = ab[0][128 + colg];
    const float c_r = ab[1][colg]      + b_hh[colg];
    const float c_z = ab[1][64 + colg] + b_hh[64 + colg];
    const float c_n = ab[1][128 + colg];
    const float bhn = b_hh[128 + colg];
    const float pb  = pred_b[0];

    int   toff[6];
    float gbr[6], mf[6];
#pragma unroll
    for (int jj = 0; jj < 6; jj++) {
        int i = tid + jj * 512;
        if (i < C2) {
            int c = i / 53, d = i - 53 * c;
            toff[jj] = c * 56 + d;
            gbr[jj]  = gate_bias[i];
        } else toff[jj] = 0;
        mf[jj] = 0.f;
    }

    const float4* wr = (const float4*)(w_hh + colg * 64);
    const float4* wz = (const float4*)(w_hh + (64 + colg) * 64);
    const float4* wn = (const float4*)(w_hh + (128 + colg) * 64);

    for (int t = 0; t < Tt; t++) {
        if (tid < Cc) {
            float xv = x[(b * Tt + t) * Cc + tid];
            xc[tid] = xv;
            if (t >= 1) out_xcopy[(b * 255 + (t - 1)) * Cc + tid] = xv;
        }
        __syncthreads();

        // ---- GRU: gh = h @ w_hh^T, then gates -> h_gru (in place in hh) ----
        {
            float hr[7], hz[7], hn[7];
#pragma unroll
            for (int r = 0; r < 7; r++) { hr[r] = 0.f; hz[r] = 0.f; hn[r] = 0.f; }
#pragma unroll 4
            for (int kc = 0; kc < 16; kc++) {
                float4 wrv = wr[kc], wzv = wz[kc], wnv = wn[kc];
#pragma unroll
                for (int r = 0; r < 7; r++) {
                    int c = rsub + 8 * r;
                    float4 hv = *(const float4*)(&hh[c][0] + kc * 4);
                    hr[r] += hv.x * wrv.x + hv.y * wrv.y + hv.z * wrv.z + hv.w * wrv.w;
                    hz[r] += hv.x * wzv.x + hv.y * wzv.y + hv.z * wzv.z + hv.w * wzv.w;
                    hn[r] += hv.x * wnv.x + hv.y * wnv.y + hv.z * wnv.z + hv.w * wnv.w;
                }
            }
            __syncthreads();    // all reads of hh done
#pragma unroll
            for (int r = 0; r < 7; r++) {
                int c = rsub + 8 * r;
                float xv = xc[c];
                float rr = sigmoidf_(xv * a_r + c_r + hr[r]);
                float zz = sigmoidf_(xv * a_z + c_z + hz[r]);
                float nn = tanhf(xv * a_n + c_n + rr * (hn[r] + bhn));
                float hp = hh[c][colg];
                hh[c][colg] = (1.f - zz) * nn + zz * hp;
            }
            __syncthreads();
        }

        // ---- q / k MLP chains (f16 LDS intermediates, in-place layers) ----
        mlp_layer<64,  false, true >(&hh[0][0], qw0, qb0, &qs[0][0], colg, rsub);
        mlp_layer<128, true,  true >(&qs[0][0], qw1, qb1, &qs[0][0], colg, rsub);
        mlp_layer<128, true,  false>(&qs[0][0], qw2, qb2, &qs[0][0], colg, rsub);
        mlp_layer<64,  false, true >(&hh[0][0], kw0, kb0, &ks[0][0], colg, rsub);
        mlp_layer<128, true,  true >(&ks[0][0], kw1, kb1, &ks[0][0], colg, rsub);
        mlp_layer<128, true,  false>(&ks[0][0], kw2, kb2, &ks[0][0], colg, rsub);

        // ---- transfer = q @ k^T  + Frobenius norm reduction ----
        {
            float acc[7];
#pragma unroll
            for (int r = 0; r < 7; r++) acc[r] = 0.f;
            const int dd = (colg < 56) ? colg : 55;
            const __half* kp = &ks[dd][0];
#pragma unroll 4
            for (int kc = 0; kc < 32; kc++) {
                float4 kv = load4h(kp + kc * 4);
#pragma unroll
                for (int r = 0; r < 7; r++) {
                    int c = rsub + 8 * r;
                    float4 qv = load4h(&qs[c][0] + kc * 4);
                    acc[r] += qv.x * kv.x + qv.y * kv.y + qv.z * kv.z + qv.w * kv.w;
                }
            }
            float ssq = 0.f;
#pragma unroll
            for (int r = 0; r < 7; r++) {
                int c = rsub + 8 * r;
                if (c < 53 && colg < 53) {
                    tr[c][colg] = acc[r];
                    ssq += acc[r] * acc[r];
                }
            }
#pragma unroll
            for (int off = 32; off > 0; off >>= 1) ssq += __shfl_down(ssq, off);
            if ((tid & 63) == 0) red[wv] = ssq;
            __syncthreads();
            if (tid == 0) {
                float s = 0.f;
                for (int w8 = 0; w8 < 8; w8++) s += red[w8];
                s_inv = 1.f / sqrtf(s);
            }
            __syncthreads();
        }

        // ---- normalize, gate, emit mix, accumulate mean_FNC ----
        {
            const float inv = s_inv;
            float* trp = &tr[0][0];
            const int mixbase = (b * Tt + t) * C2;
#pragma unroll
            for (int jj = 0; jj < 6; jj++) {
                int i = tid + jj * 512;
                if (i < C2) {
                    float v = trp[toff[jj]] * inv;
                    float g = sigmoidf_(fabsf(v) + gbr[jj]);
                    v *= g;
                    trp[toff[jj]] = v;
                    out_mix[mixbase + i] = v;
                    mf[jj] += v;
                }
            }
            __syncthreads();
        }

        // ---- h_new = transfer @ h_gru (in place in hh) ----
        {
            float acc[7];
#pragma unroll
            for (int r = 0; r < 7; r++) acc[r] = 0.f;
#pragma unroll 4
            for (int d4 = 0; d4 < 52; d4 += 4) {
                float h0 = hh[d4 + 0][colg];
                float h1 = hh[d4 + 1][colg];
                float h2 = hh[d4 + 2][colg];
                float h3 = hh[d4 + 3][colg];
#pragma unroll
                for (int r = 0; r < 7; r++) {
                    int c = rsub + 8 * r;
                    float4 tv = *(const float4*)(&tr[c][0] + d4);
                    acc[r] += tv.x * h0 + tv.y * h1 + tv.z * h2 + tv.w * h3;
                }
            }
            {
                float h52 = hh[52][colg];
#pragma unroll
                for (int r = 0; r < 7; r++) {
                    int c = rsub + 8 * r;
                    acc[r] += tr[c][52] * h52;
                }
            }
            __syncthreads();    // all reads of hh (h_gru) done
#pragma unroll
            for (int r = 0; r < 7; r++) {
                int c = rsub + 8 * r;
                hh[c][colg] = acc[r];
            }
            __syncthreads();
        }

        // ---- predicted (uses hs[:, :-1] => steps 0..254) ----
        if (t < 255 && tid < Cc) {
            const float4* hp = (const float4*)&hh[tid][0];
            const float4* pw = (const float4*)pred_w;
            float s = pb;
#pragma unroll 4
            for (int e = 0; e < 16; e++) {
                float4 hv = hp[e], wvv = pw[e];
                s += hv.x * wvv.x + hv.y * wvv.y + hv.z * wvv.z + hv.w * wvv.w;
            }
            out_pred[(b * 255 + t) * Cc + tid] = s;
        }
        __syncthreads();
    }

    // ---- mean_FNC ----
#pragma unroll
    for (int jj = 0; jj < 6; jj++) {
        int i = tid + jj * 512;
        if (i < C2) out_meanF[b * C2 + i] = mf[jj] * (1.f / 256.f);
    }
}

// Tiled GEMM: out = relu(A[M][K] @ W[N][K]^T + bias). 128x128 tile, 8x8/thread.
// AHALF: A is __half.  COLSUM: instead of storing, relu + column-sum per batch
// (rows grouped by 256) into colsum_out via atomics (z2 path).
template<bool AHALF, bool COLSUM>
__global__ __launch_bounds__(256)
void clf_gemm(const void* __restrict__ Ap,
              const float* __restrict__ W,
              const float* __restrict__ bias,
              __half* __restrict__ z_out,
              float* __restrict__ colsum_out,
              int M, int N, int K)
{
    __shared__ __align__(16) float As[16][136];
    __shared__ __align__(16) float Bs[16][136];
    const int tid = threadIdx.x;
    const int m0 = blockIdx.x * 128;
    const int n0 = blockIdx.y * 128;
    const int tx = tid & 15, ty = tid >> 4;
    float acc[8][8];
#pragma unroll
    for (int i = 0; i < 8; i++)
#pragma unroll
        for (int j = 0; j < 8; j++) acc[i][j] = 0.f;

    const int srow = tid >> 1;
    const int skk  = (tid & 1) * 8;

    for (int k0 = 0; k0 < K; k0 += 16) {
        {
            const int gr = m0 + srow;
            const size_t abase = (size_t)gr * K + k0 + skk;
#pragma unroll
            for (int j = 0; j < 8; j++) {
                int k = k0 + skk + j;
                float v = 0.f;
                if (k < K) {
                    if constexpr (AHALF) v = __half2float(((const __half*)Ap)[abase + j]);
                    else                 v = ((const float*)Ap)[abase + j];
                }
                As[skk + j][srow] = v;
            }
            const int gc = n0 + srow;
            const size_t bbase = (size_t)gc * K + k0 + skk;
#pragma unroll
            for (int j = 0; j < 8; j++) {
                int k = k0 + skk + j;
                float v = 0.f;
                if (k < K && gc < N) v = W[bbase + j];
                Bs[skk + j][srow] = v;
            }
        }
        __syncthreads();
#pragma unroll
        for (int k = 0; k < 16; k++) {
            float4 A0 = *(const float4*)&As[k][ty * 8];
            float4 A1 = *(const float4*)&As[k][ty * 8 + 4];
            float4 B0 = *(const float4*)&Bs[k][tx * 8];
            float4 B1 = *(const float4*)&Bs[k][tx * 8 + 4];
            float av[8] = {A0.x, A0.y, A0.z, A0.w, A1.x, A1.y, A1.z, A1.w};
            float bv[8] = {B0.x, B0.y, B0.z, B0.w, B1.x, B1.y, B1.z, B1.w};
#pragma unroll
            for (int i = 0; i < 8; i++)
#pragma unroll
                for (int j = 0; j < 8; j++)
                    acc[i][j] += av[i] * bv[j];
        }
        __syncthreads();
    }

    if constexpr (!COLSUM) {
#pragma unroll
        for (int i = 0; i < 8; i++) {
            int m = m0 + ty * 8 + i;
#pragma unroll
            for (int j = 0; j < 8; j++) {
                int n = n0 + tx * 8 + j;
                if (n < N) {
                    float v = fmaxf(acc[i][j] + bias[n], 0.f);
                    z_out[(size_t)m * N + n] = __float2half(v);
                }
            }
        }
    } else {
        float csum[8];
#pragma unroll
        for (int j = 0; j < 8; j++) {
            int n = n0 + tx * 8 + j;
            float bj = (n < N) ? bias[n] : 0.f;
            float s = 0.f;
#pragma unroll
            for (int i = 0; i < 8; i++) s += fmaxf(acc[i][j] + bj, 0.f);
            csum[j] = s;
        }
#pragma unroll
        for (int j = 0; j < 8; j++) As[ty][tx * 8 + j] = csum[j];
        __syncthreads();
        if (tid < 128) {
            int n = n0 + tid;
            if (n < N) {
                float s = 0.f;
#pragma unroll
                for (int r = 0; r < 16; r++) s += As[r][tid];
                atomicAdd(&colsum_out[(m0 >> 8) * 704 + n], s);
            }
        }
    }
}

__global__ __launch_bounds__(128)
void logits_kernel(const float* __restrict__ zsum,
                   const float* __restrict__ w2,
                   const float* __restrict__ b2,
                   float* __restrict__ out)
{
    int tid = threadIdx.x;          // 128 threads: (b, o) pairs
    int bb = tid >> 1, o = tid & 1;
    const float* zs = zsum + bb * 704;
    const float* wrow = w2 + o * 702;
    float s = 0.f;
    for (int j = 0; j < 702; j++) s += zs[j] * wrow[j];
    out[bb * 2 + o] = s * (1.f / 256.f) + b2[o];
}

extern "C" void kernel_launch(void* const* d_in, const int* in_sizes, int n_in,
                              void* d_out, int out_size, void* d_ws, size_t ws_size,
                              hipStream_t stream)
{
    const float* x      = (const float*)d_in[0];
    const float* w_emb  = (const float*)d_in[1];
    const float* b_emb  = (const float*)d_in[2];
    const float* w_ih   = (const float*)d_in[3];
    const float* w_hh   = (const float*)d_in[4];
    const float* b_ih   = (const float*)d_in[5];
    const float* b_hh   = (const float*)d_in[6];
    const float* qw0 = (const float*)d_in[7];
    const float* qb0 = (const float*)d_in[8];
    const float* qw1 = (const float*)d_in[9];
    const float* qb1 = (const float*)d_in[10];
    const float* qw2 = (const float*)d_in[11];
    const float* qb2 = (const float*)d_in[12];
    const float* kw0 = (const float*)d_in[13];
    const float* kb0 = (const float*)d_in[14];
    const float* kw1 = (const float*)d_in[15];
    const float* kb1 = (const float*)d_in[16];
    const float* kw2 = (const float*)d_in[17];
    const float* kb2 = (const float*)d_in[18];
    const float* gate_bias = (const float*)d_in[19];
    const float* pred_w = (const float*)d_in[20];
    const float* pred_b = (const float*)d_in[21];
    const float* cw0 = (const float*)d_in[22];
    const float* cb0 = (const float*)d_in[23];
    const float* cw1 = (const float*)d_in[24];
    const float* cb1 = (const float*)d_in[25];
    const float* cw2 = (const float*)d_in[26];
    const float* cb2 = (const float*)d_in[27];

    // output layout: logits(128) | mean_FNC(179776) | mix(46022656) |
    //                predicted(864960) | x[:,1:,:](864960)
    float* out        = (float*)d_out;
    float* out_logits = out;
    float* out_meanF  = out + 128;
    float* out_mix    = out + 128 + 179776;
    float* out_pred   = out_mix + 46022656;
    float* out_xcopy  = out_pred + 864960;

    float*  zsum = (float*)d_ws;                       // 64*704 fp32
    __half* z1   = (__half*)((char*)d_ws + (1 << 18)); // 16384*1404 f16

    hipMemsetAsync(zsum, 0, 64 * 704 * sizeof(float), stream);

    scan_kernel<<<64, 512, 0, stream>>>(
        x, w_emb, b_emb, w_ih, w_hh, b_ih, b_hh,
        qw0, qb0, qw1, qb1, qw2, qb2,
        kw0, kb0, kw1, kb1, kw2, kb2,
        gate_bias, pred_w, pred_b,
        out_meanF, out_mix, out_pred, out_xcopy);

    // z1 = relu(mix @ cw0^T + cb0): 16384 x 1404, K=2809
    clf_gemm<false, false><<<dim3(128, 11), 256, 0, stream>>>(
        out_mix, cw0, cb0, z1, nullptr, 16384, 1404, 2809);

    // z2 = relu(z1 @ cw1^T + cb1), column-summed per batch: 16384 x 702, K=1404
    clf_gemm<true, true><<<dim3(128, 6), 256, 0, stream>>>(
        z1, cw1, cb1, nullptr, zsum, 16384, 702, 1404);

    logits_kernel<<<1, 128, 0, stream>>>(zsum, cw2, cb2, out_logits);
}

// Round 2
// 5996.590 us; speedup vs baseline: 4.0112x; 4.0112x over previous
//
#include <hip/hip_runtime.h>
#include <hip/hip_fp16.h>

typedef _Float16 f16;
typedef f16 f16x4 __attribute__((ext_vector_type(4)));
typedef f16 f16x8 __attribute__((ext_vector_type(8)));
typedef float f32x4 __attribute__((ext_vector_type(4)));

#define DEVINL __device__ __forceinline__
#define MFMA16(a, b, c) __builtin_amdgcn_mfma_f32_16x16x32_f16(a, b, c, 0, 0, 0)

DEVINL float sigmoidf_(float v) { return 1.f / (1.f + __expf(-v)); }

// LDS byte offsets
// hh   f32 [56][68]            @ 0      (15232 B)   fp32 state (h / h_gru / h_new)
// hK   f16 frag [2][4][64][8]  @ 15232  (8192 B)    B[k=feat][n=ch]  (h, then h_gru, then h_new)
// hC   f16 frag [2][4][64][8]  @ 23424  (8192 B)    B[k=ch][n=feat]  (h_gru, for h_new matmul)
// qk0  f16 frag [4][4][64][8]  @ 31616  (16384 B)   q chain buffer   (also gh overlay + trK overlay)
// qk1  f16 frag [4][4][64][8]  @ 48000  (16384 B)   k chain buffer   (gh overlay tail)
// xc   f32 [56]                @ 64384  (224 B)
// pw   f32 [64]                @ 64608  (256 B)
// red  f32 [9]                 @ 64864  (36 B)
// total 64900 <= 65536

__global__ __launch_bounds__(512)
void scan_kernel(const float* __restrict__ x,
                 const float* __restrict__ w_emb,
                 const float* __restrict__ b_emb,
                 const float* __restrict__ w_ih,
                 const float* __restrict__ w_hh,
                 const float* __restrict__ b_ih,
                 const float* __restrict__ b_hh,
                 const float* __restrict__ qw0, const float* __restrict__ qb0,
                 const float* __restrict__ qw1, const float* __restrict__ qb1,
                 const float* __restrict__ qw2, const float* __restrict__ qb2,
                 const float* __restrict__ kw0, const float* __restrict__ kb0,
                 const float* __restrict__ kw1, const float* __restrict__ kb1,
                 const float* __restrict__ kw2, const float* __restrict__ kb2,
                 const float* __restrict__ gate_bias,
                 const float* __restrict__ pred_w,
                 const float* __restrict__ pred_b,
                 float* __restrict__ out_meanF,
                 float* __restrict__ out_mix,
                 float* __restrict__ out_pred,
                 float* __restrict__ out_xcopy)
{
    __shared__ __align__(16) unsigned char smem[64900];
    float* hh  = (float*)smem;
    f16*   hK  = (f16*)(smem + 15232);
    f16*   hC  = (f16*)(smem + 23424);
    f16*   qk0 = (f16*)(smem + 31616);
    f16*   qk1 = (f16*)(smem + 48000);
    f16*   gh  = (f16*)(smem + 31616);   // [192][68] f16 = 26112 B, overlays qk0+part of qk1
    f16*   trK = (f16*)(smem + 31616);   // overlays qk0 (q dead by then)
    float* xc  = (float*)(smem + 64384);
    float* pw  = (float*)(smem + 64608);
    float* red = (float*)(smem + 64864);

    const int b    = blockIdx.x;
    const int tid  = threadIdx.x;
    const int wv   = tid >> 6;
    const int lane = tid & 63;
    const int quad = lane >> 4;
    const int l15  = lane & 15;
    const int colg = (wv << 3) + (lane >> 3);   // 0..63 feature index (gate phase)
    const int rsub = lane & 7;                  // gate phase rows c = rsub + 8r

#define FRAG(buf, kt, nt) ((buf) + ((((kt) * 4 + (nt)) * 64 + lane) * 8))

    // ---------------- init: zero LDS state ----------------
    for (int i = tid; i < 56 * 68; i += 512) hh[i] = 0.f;
    for (int i = tid; i < 4096; i += 512) { hK[i] = (f16)0.f; hC[i] = (f16)0.f; }
    if (tid < 56) xc[tid] = 0.f;
    if (tid < 64) pw[tid] = pred_w[tid];

    // ---------------- per-thread GRU gate constants (embedding folded) ----------------
    float a_r = 0.f, a_z = 0.f, a_n = 0.f, s_r = 0.f, s_z = 0.f, s_n = 0.f;
    for (int e = 0; e < 64; e++) {
        float we = w_emb[e], be = b_emb[e];
        float w0 = w_ih[colg * 64 + e];
        float w1 = w_ih[(64 + colg) * 64 + e];
        float w2 = w_ih[(128 + colg) * 64 + e];
        a_r += w0 * we; s_r += w0 * be;
        a_z += w1 * we; s_z += w1 * be;
        a_n += w2 * we; s_n += w2 * be;
    }
    const float c_r = s_r + b_ih[colg] + b_hh[colg];
    const float c_z = s_z + b_ih[64 + colg] + b_hh[64 + colg];
    const float c_n = s_n + b_ih[128 + colg];
    const float bhn = b_hh[128 + colg];
    const float pb  = pred_b[0];

    // ---------------- persistent weight A-fragments in VGPRs ----------------
    // A-frag layout: A[m = l15][k = quad*8 + j], frag (mt, kt): rows mt*16+l15, cols kt*32+quad*8..+7
    auto ldfrag = [&](const float* W, int K, int mt, int kt) -> f16x8 {
        const float* p = W + (size_t)(mt * 16 + l15) * K + kt * 32 + quad * 8;
        float4 u0 = *(const float4*)p;
        float4 u1 = *(const float4*)(p + 4);
        f16x8 a;
        a[0] = (f16)u0.x; a[1] = (f16)u0.y; a[2] = (f16)u0.z; a[3] = (f16)u0.w;
        a[4] = (f16)u1.x; a[5] = (f16)u1.y; a[6] = (f16)u1.z; a[7] = (f16)u1.w;
        return a;
    };

    const int mtLo = (6 * wv) >> 2, mtHi = (6 * wv + 5) >> 2;   // GRU m-tiles for this wave
    f16x8 wg0k0 = ldfrag(w_hh, 64, mtLo, 0), wg0k1 = ldfrag(w_hh, 64, mtLo, 1);
    f16x8 wg1k0 = ldfrag(w_hh, 64, mtHi, 0), wg1k1 = ldfrag(w_hh, 64, mtHi, 1);

    f16x8 wq0f[2], wk0f[2], wq1f[4], wq2f[4], wk1f[4], wk2f[4];
#pragma unroll
    for (int kt = 0; kt < 2; kt++) {
        wq0f[kt] = ldfrag(qw0, 64, wv, kt);
        wk0f[kt] = ldfrag(kw0, 64, wv, kt);
    }
#pragma unroll
    for (int kt = 0; kt < 4; kt++) {
        wq1f[kt] = ldfrag(qw1, 128, wv, kt);
        wq2f[kt] = ldfrag(qw2, 128, wv, kt);
        wk1f[kt] = ldfrag(kw1, 128, wv, kt);
        wk2f[kt] = ldfrag(kw2, 128, wv, kt);
    }

    // MLP biases: f = wv*16 + quad*4 + reg
    const int f0 = wv * 16 + quad * 4;
    f32x4 bq0v, bq1v, bq2v, bk0v, bk1v, bk2v;
#pragma unroll
    for (int r = 0; r < 4; r++) {
        bq0v[r] = qb0[f0 + r]; bq1v[r] = qb1[f0 + r]; bq2v[r] = qb2[f0 + r];
        bk0v[r] = kb0[f0 + r]; bk1v[r] = kb1[f0 + r]; bk2v[r] = kb2[f0 + r];
    }

    // transfer / h_new tile assignment: this wave owns C-tiles (tmt, tnt0) and (tmt, tnt0+1)
    const int tmt = wv & 3, tnt0 = (wv >> 2) * 2;
    float gbv[8], mf[8];
#pragma unroll
    for (int i = 0; i < 2; i++)
#pragma unroll
        for (int r = 0; r < 4; r++) {
            int c = tmt * 16 + quad * 4 + r, d = (tnt0 + i) * 16 + l15;
            gbv[i * 4 + r] = (c < 53 && d < 53) ? gate_bias[c * 53 + d] : 0.f;
            mf[i * 4 + r] = 0.f;
        }

    // C/D tile -> B-frag-linear write: one ds_write_b64 per tile per lane.
    // element (row f = MT*16+quad*4+reg, col c = ct*16+l15) -> frag(kt=f>>5, nt=ct),
    // lane'' = l15 + 16*((f>>3)&3), j = f&7
    auto cwrite = [&](f16* dst, int ct, const f32x4 acc, const f32x4 bv, bool rel) {
        const int kts  = wv >> 1;
        const int sub  = (2 * wv + (quad >> 1)) & 3;
        const int base = ((kts * 4 + ct) * 64 + (l15 + 16 * sub)) * 8 + (quad & 1) * 4;
        f16x4 p;
#pragma unroll
        for (int r = 0; r < 4; r++) {
            float v = acc[r] + bv[r];
            if (rel) v = fmaxf(v, 0.f);
            p[r] = (f16)v;
        }
        *(f16x4*)(dst + base) = p;
    };

    __syncthreads();

    f16x8 bf[4][4];

#define PRELOAD(SRC) do { \
    _Pragma("unroll") for (int ct = 0; ct < 4; ct++) \
        _Pragma("unroll") for (int kt = 0; kt < 4; kt++) \
            bf[ct][kt] = *(const f16x8*)FRAG(SRC, kt, ct); } while (0)

#define MLP4(WF, DST, BV, REL) do { \
    f32x4 a0 = {0.f,0.f,0.f,0.f}, a1 = {0.f,0.f,0.f,0.f}; \
    f32x4 a2 = {0.f,0.f,0.f,0.f}, a3 = {0.f,0.f,0.f,0.f}; \
    _Pragma("unroll") for (int kt = 0; kt < 4; kt++) { \
        a0 = MFMA16(WF[kt], bf[0][kt], a0); \
        a1 = MFMA16(WF[kt], bf[1][kt], a1); \
        a2 = MFMA16(WF[kt], bf[2][kt], a2); \
        a3 = MFMA16(WF[kt], bf[3][kt], a3); } \
    cwrite(DST, 0, a0, BV, REL); cwrite(DST, 1, a1, BV, REL); \
    cwrite(DST, 2, a2, BV, REL); cwrite(DST, 3, a3, BV, REL); } while (0)

    for (int t = 0; t < 256; t++) {
        // ---- P0: load x[t] ----
        if (tid < 53) {
            float xv = x[(b * 256 + t) * 53 + tid];
            xc[tid] = xv;
            if (t >= 1) out_xcopy[(b * 255 + (t - 1)) * 53 + tid] = xv;
        }
        // ---- P1: gh^T = w_hh . h^T  (writes gh f16 [192][68]) ----
        {
#pragma unroll
            for (int i = 0; i < 6; i++) {
                int tau = 6 * wv + i, mt = tau >> 2, ct = tau & 3;
                bool hi = (mt != mtLo);
                f32x4 acc = {0.f, 0.f, 0.f, 0.f};
                acc = MFMA16(hi ? wg1k0 : wg0k0, *(const f16x8*)FRAG(hK, 0, ct), acc);
                acc = MFMA16(hi ? wg1k1 : wg0k1, *(const f16x8*)FRAG(hK, 1, ct), acc);
                int gbase = (mt * 16 + quad * 4) * 68 + ct * 16 + l15;
#pragma unroll
                for (int r = 0; r < 4; r++) gh[gbase + r * 68] = (f16)acc[r];
            }
        }
        __syncthreads();  // A
        // ---- P2: gates -> h_gru (hh f32, hK featK f16, hC chK f16) ----
        {
#pragma unroll
            for (int r = 0; r < 7; r++) {
                int c = rsub + 8 * r;
                float hr = (float)gh[colg * 68 + c];
                float hz = (float)gh[(64 + colg) * 68 + c];
                float hn = (float)gh[(128 + colg) * 68 + c];
                float xv = xc[c];
                float hp = hh[c * 68 + colg];
                float rr = sigmoidf_(xv * a_r + c_r + hr);
                float zz = sigmoidf_(xv * a_z + c_z + hz);
                float nn = tanhf(xv * a_n + c_n + rr * (hn + bhn));
                float hg = (1.f - zz) * nn + zz * hp;
                hh[c * 68 + colg] = hg;
                f16 h6 = (f16)hg;
                hK[(((colg >> 5) * 4 + (c >> 4)) * 64 + (c & 15) + 16 * ((colg >> 3) & 3)) * 8 + (colg & 7)] = h6;
                hC[(((c >> 5) * 4 + (colg >> 4)) * 64 + (colg & 15) + 16 * ((c >> 3) & 3)) * 8 + (c & 7)] = h6;
            }
        }
        __syncthreads();  // B
        // ---- P3: q-L0 and k-L0 (read hK, write qk0/qk1) ----
        {
            f32x4 a0 = {0.f,0.f,0.f,0.f}, a1 = {0.f,0.f,0.f,0.f};
            f32x4 a2 = {0.f,0.f,0.f,0.f}, a3 = {0.f,0.f,0.f,0.f};
#pragma unroll
            for (int kt = 0; kt < 2; kt++) {
                a0 = MFMA16(wq0f[kt], *(const f16x8*)FRAG(hK, kt, 0), a0);
                a1 = MFMA16(wq0f[kt], *(const f16x8*)FRAG(hK, kt, 1), a1);
                a2 = MFMA16(wq0f[kt], *(const f16x8*)FRAG(hK, kt, 2), a2);
                a3 = MFMA16(wq0f[kt], *(const f16x8*)FRAG(hK, kt, 3), a3);
            }
            cwrite(qk0, 0, a0, bq0v, true); cwrite(qk0, 1, a1, bq0v, true);
            cwrite(qk0, 2, a2, bq0v, true); cwrite(qk0, 3, a3, bq0v, true);
            f32x4 k0 = {0.f,0.f,0.f,0.f}, k1 = {0.f,0.f,0.f,0.f};
            f32x4 k2 = {0.f,0.f,0.f,0.f}, k3 = {0.f,0.f,0.f,0.f};
#pragma unroll
            for (int kt = 0; kt < 2; kt++) {
                k0 = MFMA16(wk0f[kt], *(const f16x8*)FRAG(hK, kt, 0), k0);
                k1 = MFMA16(wk0f[kt], *(const f16x8*)FRAG(hK, kt, 1), k1);
                k2 = MFMA16(wk0f[kt], *(const f16x8*)FRAG(hK, kt, 2), k2);
                k3 = MFMA16(wk0f[kt], *(const f16x8*)FRAG(hK, kt, 3), k3);
            }
            cwrite(qk1, 0, k0, bk0v, true); cwrite(qk1, 1, k1, bk0v, true);
            cwrite(qk1, 2, k2, bk0v, true); cwrite(qk1, 3, k3, bk0v, true);
        }
        __syncthreads();  // C
        // ---- L1/L2 in place: preload-all, barrier, mfma+write ----
        PRELOAD(qk0);
        __syncthreads();  // D
        MLP4(wq1f, qk0, bq1v, true);
        PRELOAD(qk1);
        __syncthreads();  // E
        MLP4(wk1f, qk1, bk1v, true);
        PRELOAD(qk0);
        __syncthreads();  // F
        MLP4(wq2f, qk0, bq2v, false);
        PRELOAD(qk1);
        __syncthreads();  // G
        MLP4(wk2f, qk1, bk2v, false);
        __syncthreads();  // H
        // ---- P7: transfer = q . k^T (C-tiles in regs) + Frobenius reduce ----
        f32x4 tacc0 = {0.f,0.f,0.f,0.f}, tacc1 = {0.f,0.f,0.f,0.f};
        {
            f16x8 qa[4];
#pragma unroll
            for (int kt = 0; kt < 4; kt++) qa[kt] = *(const f16x8*)FRAG(qk0, kt, tmt);
#pragma unroll
            for (int kt = 0; kt < 4; kt++) {
                tacc0 = MFMA16(qa[kt], *(const f16x8*)FRAG(qk1, kt, tnt0), tacc0);
                tacc1 = MFMA16(qa[kt], *(const f16x8*)FRAG(qk1, kt, tnt0 + 1), tacc1);
            }
            float ssq = 0.f;
#pragma unroll
            for (int r = 0; r < 4; r++) {
                int c = tmt * 16 + quad * 4 + r;
                if (c < 53) {
                    if (tnt0 * 16 + l15 < 53)       ssq += tacc0[r] * tacc0[r];
                    if ((tnt0 + 1) * 16 + l15 < 53) ssq += tacc1[r] * tacc1[r];
                }
            }
#pragma unroll
            for (int off = 32; off > 0; off >>= 1) ssq += __shfl_down(ssq, off);
            if (lane == 0) red[wv] = ssq;
        }
        __syncthreads();  // I
        if (tid == 0) {
            float s2 = 0.f;
            for (int w8 = 0; w8 < 8; w8++) s2 += red[w8];
            red[8] = rsqrtf(s2);
        }
        __syncthreads();  // J
        // ---- P8: normalize, gate, emit mix, write trK (A-frags of transfer) ----
        {
            const float inv = red[8];
            const int mixbase = (b * 256 + t) * 2809;
#pragma unroll
            for (int i = 0; i < 2; i++)
#pragma unroll
                for (int r = 0; r < 4; r++) {
                    int c = tmt * 16 + quad * 4 + r;
                    int d = (tnt0 + i) * 16 + l15;
                    float v = (i == 0 ? tacc0[r] : tacc1[r]) * inv;
                    float g = sigmoidf_(fabsf(v) + gbv[i * 4 + r]);
                    v *= g;
                    bool ok = (c < 53) & (d < 53);
                    v = ok ? v : 0.f;
                    if (ok) out_mix[mixbase + c * 53 + d] = v;
                    mf[i * 4 + r] += v;
                    trK[(((d >> 5) * 4 + (c >> 4)) * 64 + (c & 15) + 16 * ((d >> 3) & 3)) * 8 + (d & 7)] = (f16)v;
                }
        }
        __syncthreads();  // K
        // ---- P9: h_new = transfer . h_gru (A = trK, B = hC) ----
        {
            f32x4 h0 = {0.f,0.f,0.f,0.f}, h1 = {0.f,0.f,0.f,0.f};
            f16x8 ta0 = *(const f16x8*)FRAG(trK, 0, tmt);
            f16x8 ta1 = *(const f16x8*)FRAG(trK, 1, tmt);
            h0 = MFMA16(ta0, *(const f16x8*)FRAG(hC, 0, tnt0), h0);
            h0 = MFMA16(ta1, *(const f16x8*)FRAG(hC, 1, tnt0), h0);
            h1 = MFMA16(ta0, *(const f16x8*)FRAG(hC, 0, tnt0 + 1), h1);
            h1 = MFMA16(ta1, *(const f16x8*)FRAG(hC, 1, tnt0 + 1), h1);
#pragma unroll
            for (int i = 0; i < 2; i++)
#pragma unroll
                for (int r = 0; r < 4; r++) {
                    int c = tmt * 16 + quad * 4 + r;
                    int e = (tnt0 + i) * 16 + l15;
                    float v = (i == 0 ? h0[r] : h1[r]);
                    if (c < 56) hh[c * 68 + e] = v;
                    hK[(((e >> 5) * 4 + (c >> 4)) * 64 + (c & 15) + 16 * ((e >> 3) & 3)) * 8 + (e & 7)] = (f16)v;
                }
        }
        __syncthreads();  // L
        // ---- P10: predicted (hs[:, :-1] => t < 255) ----
        if (t < 255 && tid < 53) {
            const float* hrow = hh + tid * 68;
            float s = pb;
#pragma unroll 4
            for (int e4 = 0; e4 < 16; e4++) {
                float4 hv = *(const float4*)(hrow + e4 * 4);
                float4 wv4 = *(const float4*)(pw + e4 * 4);
                s += hv.x * wv4.x + hv.y * wv4.y + hv.z * wv4.z + hv.w * wv4.w;
            }
            out_pred[(b * 255 + t) * 53 + tid] = s;
        }
    }

    // ---- mean_FNC from per-lane accumulators ----
#pragma unroll
    for (int i = 0; i < 2; i++)
#pragma unroll
        for (int r = 0; r < 4; r++) {
            int c = tmt * 16 + quad * 4 + r;
            int d = (tnt0 + i) * 16 + l15;
            if (c < 53 && d < 53)
                out_meanF[b * 2809 + c * 53 + d] = mf[i * 4 + r] * (1.f / 256.f);
        }
#undef FRAG
#undef PRELOAD
#undef MLP4
}

// ---------------- classifier (unchanged from R1) ----------------
template<bool AHALF, bool COLSUM>
__global__ __launch_bounds__(256)
void clf_gemm(const void* __restrict__ Ap,
              const float* __restrict__ W,
              const float* __restrict__ bias,
              __half* __restrict__ z_out,
              float* __restrict__ colsum_out,
              int M, int N, int K)
{
    __shared__ __align__(16) float As[16][136];
    __shared__ __align__(16) float Bs[16][136];
    const int tid = threadIdx.x;
    const int m0 = blockIdx.x * 128;
    const int n0 = blockIdx.y * 128;
    const int tx = tid & 15, ty = tid >> 4;
    float acc[8][8];
#pragma unroll
    for (int i = 0; i < 8; i++)
#pragma unroll
        for (int j = 0; j < 8; j++) acc[i][j] = 0.f;

    const int srow = tid >> 1;
    const int skk  = (tid & 1) * 8;

    for (int k0 = 0; k0 < K; k0 += 16) {
        {
            const int gr = m0 + srow;
            const size_t abase = (size_t)gr * K + k0 + skk;
#pragma unroll
            for (int j = 0; j < 8; j++) {
                int k = k0 + skk + j;
                float v = 0.f;
                if (k < K) {
                    if constexpr (AHALF) v = __half2float(((const __half*)Ap)[abase + j]);
                    else                 v = ((const float*)Ap)[abase + j];
                }
                As[skk + j][srow] = v;
            }
            const int gc = n0 + srow;
            const size_t bbase = (size_t)gc * K + k0 + skk;
#pragma unroll
            for (int j = 0; j < 8; j++) {
                int k = k0 + skk + j;
                float v = 0.f;
                if (k < K && gc < N) v = W[bbase + j];
                Bs[skk + j][srow] = v;
            }
        }
        __syncthreads();
#pragma unroll
        for (int k = 0; k < 16; k++) {
            float4 A0 = *(const float4*)&As[k][ty * 8];
            float4 A1 = *(const float4*)&As[k][ty * 8 + 4];
            float4 B0 = *(const float4*)&Bs[k][tx * 8];
            float4 B1 = *(const float4*)&Bs[k][tx * 8 + 4];
            float av[8] = {A0.x, A0.y, A0.z, A0.w, A1.x, A1.y, A1.z, A1.w};
            float bv[8] = {B0.x, B0.y, B0.z, B0.w, B1.x, B1.y, B1.z, B1.w};
#pragma unroll
            for (int i = 0; i < 8; i++)
#pragma unroll
                for (int j = 0; j < 8; j++)
                    acc[i][j] += av[i] * bv[j];
        }
        __syncthreads();
    }

    if constexpr (!COLSUM) {
#pragma unroll
        for (int i = 0; i < 8; i++) {
            int m = m0 + ty * 8 + i;
#pragma unroll
            for (int j = 0; j < 8; j++) {
                int n = n0 + tx * 8 + j;
                if (n < N) {
                    float v = fmaxf(acc[i][j] + bias[n], 0.f);
                    z_out[(size_t)m * N + n] = __float2half(v);
                }
            }
        }
    } else {
        float csum[8];
#pragma unroll
        for (int j = 0; j < 8; j++) {
            int n = n0 + tx * 8 + j;
            float bj = (n < N) ? bias[n] : 0.f;
            float s = 0.f;
#pragma unroll
            for (int i = 0; i < 8; i++) s += fmaxf(acc[i][j] + bj, 0.f);
            csum[j] = s;
        }
#pragma unroll
        for (int j = 0; j < 8; j++) As[ty][tx * 8 + j] = csum[j];
        __syncthreads();
        if (tid < 128) {
            int n = n0 + tid;
            if (n < N) {
                float s = 0.f;
#pragma unroll
                for (int r = 0; r < 16; r++) s += As[r][tid];
                atomicAdd(&colsum_out[(m0 >> 8) * 704 + n], s);
            }
        }
    }
}

__global__ __launch_bounds__(128)
void logits_kernel(const float* __restrict__ zsum,
                   const float* __restrict__ w2,
                   const float* __restrict__ b2,
                   float* __restrict__ out)
{
    int tid = threadIdx.x;
    int bb = tid >> 1, o = tid & 1;
    const float* zs = zsum + bb * 704;
    const float* wrow = w2 + o * 702;
    float s = 0.f;
    for (int j = 0; j < 702; j++) s += zs[j] * wrow[j];
    out[bb * 2 + o] = s * (1.f / 256.f) + b2[o];
}

extern "C" void kernel_launch(void* const* d_in, const int* in_sizes, int n_in,
                              void* d_out, int out_size, void* d_ws, size_t ws_size,
                              hipStream_t stream)
{
    const float* x      = (const float*)d_in[0];
    const float* w_emb  = (const float*)d_in[1];
    const float* b_emb  = (const float*)d_in[2];
    const float* w_ih   = (const float*)d_in[3];
    const float* w_hh   = (const float*)d_in[4];
    const float* b_ih   = (const float*)d_in[5];
    const float* b_hh   = (const float*)d_in[6];
    const float* qw0 = (const float*)d_in[7];
    const float* qb0 = (const float*)d_in[8];
    const float* qw1 = (const float*)d_in[9];
    const float* qb1 = (const float*)d_in[10];
    const float* qw2 = (const float*)d_in[11];
    const float* qb2 = (const float*)d_in[12];
    const float* kw0 = (const float*)d_in[13];
    const float* kb0 = (const float*)d_in[14];
    const float* kw1 = (const float*)d_in[15];
    const float* kb1 = (const float*)d_in[16];
    const float* kw2 = (const float*)d_in[17];
    const float* kb2 = (const float*)d_in[18];
    const float* gate_bias = (const float*)d_in[19];
    const float* pred_w = (const float*)d_in[20];
    const float* pred_b = (const float*)d_in[21];
    const float* cw0 = (const float*)d_in[22];
    const float* cb0 = (const float*)d_in[23];
    const float* cw1 = (const float*)d_in[24];
    const float* cb1 = (const float*)d_in[25];
    const float* cw2 = (const float*)d_in[26];
    const float* cb2 = (const float*)d_in[27];

    float* out_logits = (float*)d_out;
    float* out_meanF  = (float*)d_out + 128;
    float* out_mix    = (float*)d_out + 128 + 179776;
    float* out_pred   = out_mix + 46022656;
    float* out_xcopy  = out_pred + 864960;

    float*  zsum = (float*)d_ws;                       // 64*704 fp32
    __half* z1   = (__half*)((char*)d_ws + (1 << 18)); // 16384*1404 f16

    hipMemsetAsync(zsum, 0, 64 * 704 * sizeof(float), stream);

    scan_kernel<<<64, 512, 0, stream>>>(
        x, w_emb, b_emb, w_ih, w_hh, b_ih, b_hh,
        qw0, qb0, qw1, qb1, qw2, qb2,
        kw0, kb0, kw1, kb1, kw2, kb2,
        gate_bias, pred_w, pred_b,
        out_meanF, out_mix, out_pred, out_xcopy);

    clf_gemm<false, false><<<dim3(128, 11), 256, 0, stream>>>(
        out_mix, cw0, cb0, z1, nullptr, 16384, 1404, 2809);

    clf_gemm<true, true><<<dim3(128, 6), 256, 0, stream>>>(
        z1, cw1, cb1, nullptr, zsum, 16384, 702, 1404);

    logits_kernel<<<1, 128, 0, stream>>>(zsum, cw2, cb2, out_logits);
}